// Round 2
// baseline (567.355 us; speedup 1.0000x reference)
//
#include <hip/hip_runtime.h>
#include <hip/hip_fp16.h>

// Problem: B=4, S=2048, H=8, E=64. BH=32 heads total.
// Pipeline: proj (q,k,v = x@W^T+b, stored [b,h,s,e] as f16 hi+lo) ->
//           maskgen (jax threefry2x32 PARTITIONABLE bernoulli bits, packed) ->
//           attn (two-pass flash: pass A l=sum exp(s-8), pass B exact
//                 p=e/(0.9 l) masked, fp16 cast, MFMA PV).
// Workspace layout (needs 64 MiB):
//   Qh 0, Ql 8M, Kh 16M, Kl 24M, Vh 32M, Vl 40M, mask 48M..64M (bytes, M=2^20*8)

typedef _Float16 f16;
typedef _Float16 f16x4 __attribute__((ext_vector_type(4)));
typedef _Float16 f16x8 __attribute__((ext_vector_type(8)));
typedef float f32x4v __attribute__((ext_vector_type(4)));
typedef unsigned int u32;

// ---------------- projection: out[f] = sum_e x[e]*W[f][e] + b[f] ----------------
// One block: 128 consecutive input tokens (tin = (b*S+s)*H + h), all 64 f.
// LDS padded stride 68 floats; thread (tx,ty): tokens tx+16i, f = 4*ty+j.
__global__ __launch_bounds__(256) void proj_kernel(
    const float* __restrict__ X, const float* __restrict__ W,
    const float* __restrict__ bias,
    f16* __restrict__ Oh, f16* __restrict__ Ol)
{
    __shared__ __align__(16) float Wl[64 * 68];
    __shared__ __align__(16) float Xl[128 * 68];
    const int t = threadIdx.x;
    const int tb = blockIdx.x * 128;

    for (int c = t; c < 1024; c += 256) {          // W: 64x64 floats
        int f = c >> 4, e4 = (c & 15) << 2;
        *(float4*)&Wl[f * 68 + e4] = *(const float4*)(W + f * 64 + e4);
    }
    for (int c = t; c < 2048; c += 256) {          // X: 128x64 floats
        int tok = c >> 4, e4 = (c & 15) << 2;
        *(float4*)&Xl[tok * 68 + e4] = *(const float4*)(X + (size_t)(tb + tok) * 64 + e4);
    }
    __syncthreads();

    const int tx = t & 15;     // token lane
    const int ty = t >> 4;     // f group
    const int f0 = ty * 4;

    float acc[8][4];
#pragma unroll
    for (int i = 0; i < 8; ++i)
#pragma unroll
        for (int j = 0; j < 4; ++j) acc[i][j] = bias[f0 + j];

    for (int e = 0; e < 64; e += 4) {
        float4 wv[4];
#pragma unroll
        for (int j = 0; j < 4; ++j) wv[j] = *(float4*)&Wl[(f0 + j) * 68 + e];
#pragma unroll
        for (int i = 0; i < 8; ++i) {
            float4 xv = *(float4*)&Xl[(tx + 16 * i) * 68 + e];
#pragma unroll
            for (int j = 0; j < 4; ++j)
                acc[i][j] += xv.x * wv[j].x + xv.y * wv[j].y + xv.z * wv[j].z + xv.w * wv[j].w;
        }
    }

#pragma unroll
    for (int i = 0; i < 8; ++i) {
        int tin = tb + tx + 16 * i;
        int h  = tin & 7;          // H=8 fastest in input
        int bs = tin >> 3;
        int b  = bs >> 11;         // S=2048
        int s  = bs & 2047;
        size_t o = ((size_t)(b * 8 + h) * 2048 + s) * 64 + f0;   // [b,h,s,e]
        f16x4 hv, lv;
#pragma unroll
        for (int j = 0; j < 4; ++j) {
            float a = acc[i][j];
            f16 hh = (f16)a;
            hv[j] = hh;
            lv[j] = (f16)(a - (float)hh);   // exact residual -> q to ~2^-22
        }
        *(f16x4*)(Oh + o) = hv;
        *(f16x4*)(Ol + o) = lv;
    }
}

// ---------------- dropout mask: jax threefry2x32, PARTITIONABLE path ----------------
// jax >= 0.4.30 default (jax_threefry_partitionable=True):
//   per flat index i over [B,H,S,S]: counter = uint64(i); x0 = hi32 = 0, x1 = lo32 = i
//   (b1,b2) = threefry2x32(key=(0,42), (x0,x1)); bits = b1 ^ b2   (32-bit width)
//   keep <=> ((bits>>9)|0x3f800000 as float)-1 < 0.9f <=> bits < 0xE6666600.
__device__ __forceinline__ u32 rotl32(u32 x, int r) { return (x << r) | (x >> (32 - r)); }

__global__ __launch_bounds__(256) void maskgen_kernel(u32* __restrict__ mask)
{
    const u32 tid = blockIdx.x * 256u + threadIdx.x;   // 0..4194303
    const u32 j0 = tid << 5;
    const u32 ks1 = 42u, ks2 = 0x1BD11BF0u;            // ks0=0; 0x1BD11BDA ^ 0 ^ 42
    u32 wm = 0u;
#pragma unroll 8
    for (u32 i = 0; i < 32u; ++i) {
        u32 x0 = 0u;                                   // hi32 counter + ks0(=0)
        u32 x1 = j0 + i + ks1;                         // lo32 counter + ks1
#define TF4(a,b,c,d) \
        x0 += x1; x1 = rotl32(x1,a); x1 ^= x0; \
        x0 += x1; x1 = rotl32(x1,b); x1 ^= x0; \
        x0 += x1; x1 = rotl32(x1,c); x1 ^= x0; \
        x0 += x1; x1 = rotl32(x1,d); x1 ^= x0;
        TF4(13,15,26,6)   x0 += ks1; x1 += ks2 + 1u;
        TF4(17,29,16,24)  x0 += ks2; x1 += 2u;
        TF4(13,15,26,6)               x1 += ks1 + 3u;
        TF4(17,29,16,24)  x0 += ks1; x1 += ks2 + 4u;
        TF4(13,15,26,6)   x0 += ks2; x1 += 5u;
#undef TF4
        u32 y = x0 ^ x1;                               // 32-bit fold of the 2x32 output
        wm |= (y < 0xE6666600u) ? (1u << i) : 0u;
    }
    mask[tid] = wm;
}

// ---------------- attention ----------------
// grid (16, 32): x = 128-row Q tile, y = bh. 4 waves x 32 rows.
// MFMA 16x16x32 f16. A-layout: A[m=lane&15][k=(lane>>4)*8+j];
// B-layout: B[k=(lane>>4)*8+j][n=lane&15]; C: row=(lane>>4)*4+r, col=lane&15.
__global__ __launch_bounds__(256, 2) void attn_kernel(
    const f16* __restrict__ Qh, const f16* __restrict__ Ql,
    const f16* __restrict__ Kh, const f16* __restrict__ Kl,
    const f16* __restrict__ Vh, const f16* __restrict__ Vl,
    const u32* __restrict__ mask, float* __restrict__ out)
{
    constexpr int LDK = 88;   // half stride: 176 B rows (16B aligned, 2-way banks)
    __shared__ __align__(16) f16 kh_l[64 * LDK];
    __shared__ __align__(16) f16 kl_l[64 * LDK];
    __shared__ __align__(16) f16 vh_l[64 * LDK];   // transposed: [dim][row]
    __shared__ __align__(16) f16 vl_l[64 * LDK];
    __shared__ __align__(16) f16 p_l[4][32 * LDK]; // per-wave P tile
    __shared__ u32 m_l[256];                       // 128 q-rows x 2 words

    const int t = threadIdx.x;
    const int w = t >> 6;
    const int lane = t & 63;
    const int lrow = lane & 15;
    const int kg = lane >> 4;
    const int qt = blockIdx.x;
    const int bh = blockIdx.y;

    // persistent Q fragments (hi/lo), 2 m-tiles x 2 k-steps
    f16x8 qh[2][2], ql[2][2];
#pragma unroll
    for (int mt = 0; mt < 2; ++mt) {
        size_t rowg = (size_t)bh * 2048 + qt * 128 + w * 32 + mt * 16 + lrow;
        const f16* ph = Qh + rowg * 64 + kg * 8;
        const f16* pl = Ql + rowg * 64 + kg * 8;
        qh[mt][0] = *(const f16x8*)(ph);
        qh[mt][1] = *(const f16x8*)(ph + 32);
        ql[mt][0] = *(const f16x8*)(pl);
        ql[mt][1] = *(const f16x8*)(pl + 32);
    }

    const size_t kbase = (size_t)bh * 2048 * 64;

    auto stage_k = [&](int kt) {
        for (int c = t; c < 512; c += 256) {
            int r = c >> 3, c8 = (c & 7) << 3;
            int g = (kt * 64 + r) * 64 + c8;
            *(uint4*)&kh_l[r * LDK + c8] = *(const uint4*)(Kh + kbase + g);
            *(uint4*)&kl_l[r * LDK + c8] = *(const uint4*)(Kl + kbase + g);
        }
    };

    // identical score computation for both passes (bit-identical chain order)
    auto compute_S = [&](f32x4v sfr[2][4]) {
#pragma unroll
        for (int mt = 0; mt < 2; ++mt)
#pragma unroll
            for (int n = 0; n < 4; ++n)
                sfr[mt][n] = f32x4v{0.f, 0.f, 0.f, 0.f};
#pragma unroll
        for (int n = 0; n < 4; ++n) {
#pragma unroll
            for (int ks = 0; ks < 2; ++ks) {
                const int off = (n * 16 + lrow) * LDK + ks * 32 + kg * 8;
                f16x8 bhf = *(const f16x8*)&kh_l[off];
                f16x8 blf = *(const f16x8*)&kl_l[off];
#pragma unroll
                for (int mt = 0; mt < 2; ++mt) {
                    sfr[mt][n] = __builtin_amdgcn_mfma_f32_16x16x32_f16(qh[mt][ks], bhf, sfr[mt][n], 0, 0, 0);
                    sfr[mt][n] = __builtin_amdgcn_mfma_f32_16x16x32_f16(ql[mt][ks], bhf, sfr[mt][n], 0, 0, 0);
                    sfr[mt][n] = __builtin_amdgcn_mfma_f32_16x16x32_f16(qh[mt][ks], blf, sfr[mt][n], 0, 0, 0);
                }
            }
        }
    };

    // ---- pass A: row sums l = sum exp(s - 8) (fixed shift; cancels in e/l) ----
    float lsum[2][4] = {{0.f, 0.f, 0.f, 0.f}, {0.f, 0.f, 0.f, 0.f}};
    for (int kt = 0; kt < 32; ++kt) {
        __syncthreads();
        stage_k(kt);
        __syncthreads();
        f32x4v sfr[2][4];
        compute_S(sfr);
#pragma unroll
        for (int mt = 0; mt < 2; ++mt)
#pragma unroll
            for (int n = 0; n < 4; ++n)
#pragma unroll
                for (int r = 0; r < 4; ++r)
                    lsum[mt][r] += __expf(fmaf(sfr[mt][n][r], 0.125f, -8.0f));
    }

    float rsc[2][4];
#pragma unroll
    for (int mt = 0; mt < 2; ++mt)
#pragma unroll
        for (int r = 0; r < 4; ++r) {
            float v = lsum[mt][r];
            v += __shfl_xor(v, 1);
            v += __shfl_xor(v, 2);
            v += __shfl_xor(v, 4);
            v += __shfl_xor(v, 8);
            rsc[mt][r] = 1.0f / (0.9f * v);   // folds dropout 1/(1-p)
        }

    // ---- pass B: recompute s, exact p, dropout, fp16 cast, PV ----
    f32x4v oacc[2][4];
#pragma unroll
    for (int mt = 0; mt < 2; ++mt)
#pragma unroll
        for (int fn = 0; fn < 4; ++fn)
            oacc[mt][fn] = f32x4v{0.f, 0.f, 0.f, 0.f};

    for (int kt = 0; kt < 32; ++kt) {
        __syncthreads();
        stage_k(kt);
        // V staged transposed [dim][row]; r = c&63 keeps LDS writes conflict-free
        for (int c = t; c < 512; c += 256) {
            int r = c & 63, d0 = (c >> 6) << 3;
            int g = (kt * 64 + r) * 64 + d0;
            uint4 hv4 = *(const uint4*)(Vh + kbase + g);
            uint4 lv4 = *(const uint4*)(Vl + kbase + g);
            const f16* hp = (const f16*)&hv4;
            const f16* lp = (const f16*)&lv4;
#pragma unroll
            for (int j = 0; j < 8; ++j) {
                vh_l[(d0 + j) * LDK + r] = hp[j];
                vl_l[(d0 + j) * LDK + r] = lp[j];
            }
        }
        {   // mask tile: 128 rows x 64 cols = 256 words
            int rb = t >> 1, wd = t & 1;
            m_l[t] = mask[(size_t)bh * 131072 + (size_t)(qt * 128 + rb) * 64 + kt * 2 + wd];
        }
        __syncthreads();

        f32x4v sfr[2][4];
        compute_S(sfr);

#pragma unroll
        for (int mt = 0; mt < 2; ++mt)
#pragma unroll
            for (int n = 0; n < 4; ++n)
#pragma unroll
                for (int r = 0; r < 4; ++r) {
                    float e = __expf(fmaf(sfr[mt][n][r], 0.125f, -8.0f));
                    float p = e * rsc[mt][r];
                    int rb = w * 32 + mt * 16 + kg * 4 + r;
                    int cc = n * 16 + lrow;
                    u32 wv = m_l[rb * 2 + (n >> 1)];
                    if (!((wv >> (cc & 31)) & 1u)) p = 0.0f;
                    p_l[w][(mt * 16 + kg * 4 + r) * LDK + cc] = (f16)p;  // RTNE, matches astype(f16)
                }

        // PV: out += P(16f exact) * (Vh + Vl)   (wave-private p_l: no barrier)
#pragma unroll
        for (int ks = 0; ks < 2; ++ks) {
            f16x8 pa0 = *(const f16x8*)&p_l[w][lrow * LDK + ks * 32 + kg * 8];
            f16x8 pa1 = *(const f16x8*)&p_l[w][(16 + lrow) * LDK + ks * 32 + kg * 8];
#pragma unroll
            for (int fn = 0; fn < 4; ++fn) {
                const int voff = (fn * 16 + lrow) * LDK + ks * 32 + kg * 8;
                f16x8 vhf = *(const f16x8*)&vh_l[voff];
                f16x8 vlf = *(const f16x8*)&vl_l[voff];
                oacc[0][fn] = __builtin_amdgcn_mfma_f32_16x16x32_f16(pa0, vhf, oacc[0][fn], 0, 0, 0);
                oacc[0][fn] = __builtin_amdgcn_mfma_f32_16x16x32_f16(pa0, vlf, oacc[0][fn], 0, 0, 0);
                oacc[1][fn] = __builtin_amdgcn_mfma_f32_16x16x32_f16(pa1, vhf, oacc[1][fn], 0, 0, 0);
                oacc[1][fn] = __builtin_amdgcn_mfma_f32_16x16x32_f16(pa1, vlf, oacc[1][fn], 0, 0, 0);
            }
        }
    }

    // epilogue: out [b,h,s,e] fp32
#pragma unroll
    for (int mt = 0; mt < 2; ++mt)
#pragma unroll
        for (int fn = 0; fn < 4; ++fn)
#pragma unroll
            for (int r = 0; r < 4; ++r) {
                int row = qt * 128 + w * 32 + mt * 16 + kg * 4 + r;
                out[((size_t)bh * 2048 + row) * 64 + fn * 16 + lrow] = oacc[mt][fn][r];
            }
}

extern "C" void kernel_launch(void* const* d_in, const int* in_sizes, int n_in,
                              void* d_out, int out_size, void* d_ws, size_t ws_size,
                              hipStream_t stream) {
    (void)in_sizes; (void)n_in; (void)out_size; (void)ws_size;
    const float* query = (const float*)d_in[0];
    const float* key_  = (const float*)d_in[1];
    const float* value = (const float*)d_in[2];
    const float* Wq = (const float*)d_in[3];
    const float* bq = (const float*)d_in[4];
    const float* Wk = (const float*)d_in[5];
    const float* bk = (const float*)d_in[6];
    const float* Wv = (const float*)d_in[7];
    const float* bv = (const float*)d_in[8];

    char* ws = (char*)d_ws;                 // needs 64 MiB
    f16* Qh = (f16*)(ws);
    f16* Ql = (f16*)(ws + 8388608);
    f16* Kh = (f16*)(ws + 16777216);
    f16* Kl = (f16*)(ws + 25165824);
    f16* Vh = (f16*)(ws + 33554432);
    f16* Vl = (f16*)(ws + 41943040);
    u32* mask = (u32*)(ws + 50331648);

    proj_kernel<<<512, 256, 0, stream>>>(query, Wq, bq, Qh, Ql);
    proj_kernel<<<512, 256, 0, stream>>>(key_,  Wk, bk, Kh, Kl);
    proj_kernel<<<512, 256, 0, stream>>>(value, Wv, bv, Vh, Vl);
    maskgen_kernel<<<16384, 256, 0, stream>>>(mask);
    attn_kernel<<<dim3(16, 32), 256, 0, stream>>>(Qh, Ql, Kh, Kl, Vh, Vl, mask, (float*)d_out);
}